// Round 13
// baseline (206.634 us; speedup 1.0000x reference)
//
#include <hip/hip_runtime.h>

#define EPSF 1e-12f
constexpr int BB = 2;
constexpr int PP = 8192;
constexpr int VV = 4098;
constexpr int FF = 8192;

constexpr int SLOW_F4 = 5;            // verbatim record: 5 x float4
constexpr int NCONST = 22;            // fast consts per triangle
constexpr int PTS_PER_BLOCK = 2048;   // 8 points/thread x 256 threads
constexpr int NSLICES = 128;
constexpr int CHUNK_T = FF / NSLICES; // 64 tris/block = 1 mask word

typedef float f2 __attribute__((ext_vector_type(2)));

__device__ __forceinline__ f2 vfma(f2 a, f2 b, f2 c) {
#if __has_builtin(__builtin_elementwise_fma)
    return __builtin_elementwise_fma(a, b, c);
#else
    return (f2){fmaf(a.x, b.x, c.x), fmaf(a.y, b.y, c.y)};
#endif
}
__device__ __forceinline__ f2 vmin2(f2 a, f2 b) { return __builtin_elementwise_min(a, b); }
__device__ __forceinline__ f2 vmax2(f2 a, f2 b) { return __builtin_elementwise_max(a, b); }
__device__ __forceinline__ f2 bc(float s) { return (f2){s, s}; }
__device__ __forceinline__ f2 clamp01(f2 x) { return vmin2(vmax2(x, bc(0.0f)), bc(1.0f)); }

// ---------------------------------------------------------------------------
// Kernel 1: pair-interleaved fast records + (flagged-only) slow records +
// sliver mask + inits. Fast consts per tri (c): 0-2 ab, 3 ka1, 4-6 ac,
// 7 ka2, 8-10 a, 11 aa*, 12 ab2, 13 ac2, 14 abac, 15 bc2, 16 kbc=ab2-abac,
// 17 iab2, 18 iac2, 19 ibc2, 20 inn, 21 nn. Interleaved per tri-PAIR
// (each f2 = even,odd tri -> wave-uniform SGPR pair, direct v_pk operand).
// Sliver poisoning: aa*=+inf => ap2/bp2/dAB/dAC/dBC/dIN all +inf (no 0*inf).
// ---------------------------------------------------------------------------
__global__ __launch_bounds__(256) void precompute_kernel(
    const float* __restrict__ verts, const int* __restrict__ faces,
    float* __restrict__ pairrec, float4* __restrict__ slowrec,
    unsigned long long* __restrict__ mask, unsigned int* __restrict__ minD,
    float* __restrict__ out)
{
    int idx = blockIdx.x * 256 + threadIdx.x;   // grid exactly covers BB*FF
    if (idx == 0) out[0] = 0.0f;                // reduce atomicAdds into it
    if (idx < BB * PP) minD[idx] = 0x7F800000u; // +inf
    if (idx >= BB * FF) return;

    int b = idx / FF;
    const float* vb = verts + (size_t)b * VV * 3;
    int i0 = faces[idx * 3 + 0];
    int i1 = faces[idx * 3 + 1];
    int i2 = faces[idx * 3 + 2];

    float ax = vb[i0*3+0], ay = vb[i0*3+1], az = vb[i0*3+2];
    float bx = vb[i1*3+0], by = vb[i1*3+1], bz = vb[i1*3+2];
    float cx = vb[i2*3+0], cy = vb[i2*3+1], cz = vb[i2*3+2];

    // plain fp32 subs: bit-match numpy (shared by both records)
    float abx = bx-ax, aby = by-ay, abz = bz-az;
    float acx = cx-ax, acy = cy-ay, acz = cz-az;
    float bcx = cx-bx, bcy = cy-by, bcz = cz-bz;

    float nx = aby*acz - abz*acy;
    float ny = abz*acx - abx*acz;
    float nz = abx*acy - aby*acx;

    float ka1  = abx*ax + aby*ay + abz*az;
    float ka2  = acx*ax + acy*ay + acz*az;
    float aa   = ax*ax + ay*ay + az*az;
    float abac = abx*acx + aby*acy + abz*acz;

    float ab2 = abx*abx + aby*aby + abz*abz;
    float ac2 = acx*acx + acy*acy + acz*acz;
    float bc2 = bcx*bcx + bcy*bcy + bcz*bcz;
    float nn  = nx*nx + ny*ny + nz*nz;

    float inv_ab2 = 1.0f / fmaxf(ab2, EPSF);
    float inv_ac2 = 1.0f / fmaxf(ac2, EPSF);
    float inv_bc2 = 1.0f / fmaxf(bc2, EPSF);
    float inv_nn  = 1.0f / fmaxf(nn,  EPSF);

    // sliver/degenerate classifier: sin^2(angle at a) <= 3e-2 or tiny edges
    bool slowtri = !((nn > 0.03f * (ab2 * ac2)) &&
                     (ab2 > 1e-4f) && (ac2 > 1e-4f) && (bc2 > 1e-4f));

    unsigned long long mb = __ballot(slowtri);
    if ((threadIdx.x & 63) == 0) mask[idx >> 6] = mb;

    if (slowtri) {  // slow record only for flagged tris (~0.8%)
        float4* t = slowrec + (size_t)idx * SLOW_F4;
        t[0] = make_float4(ax, ay, az, abx);
        t[1] = make_float4(bx, by, bz, aby);
        t[2] = make_float4(cx, cy, cz, abz);
        t[3] = make_float4(acx, acy, acz, bcx);
        t[4] = make_float4(bcy, bcz, 0.0f, 0.0f);
    }

    float INF = __uint_as_float(0x7F800000u);
    float cvals[NCONST] = {
        abx, aby, abz, ka1,
        acx, acy, acz, ka2,
        ax,  ay,  az,  slowtri ? INF : aa,
        ab2, ac2, abac, bc2,
        ab2 - abac, inv_ab2, inv_ac2, inv_bc2,
        inv_nn, nn
    };
    float* pr = pairrec + (size_t)(idx >> 1) * (2 * NCONST) + (idx & 1);
#pragma unroll
    for (int c = 0; c < NCONST; ++c) pr[2*c] = cvals[c];
}

// ---------------------------------------------------------------------------
// Verbatim fp32 port (bit-exact vs numpy) — slivers only. Proven in R3.
// ---------------------------------------------------------------------------
__device__ __forceinline__ float tri_d2(
    float px, float py, float pz,
    float4 R0, float4 R1, float4 R2, float4 R3, float4 R4)
{
#pragma clang fp contract(off)
    float ax = R0.x, ay = R0.y, az = R0.z;
    float bx = R1.x, by = R1.y, bz = R1.z;
    float cx = R2.x, cy = R2.y, cz = R2.z;
    float abx = R0.w, aby = R1.w, abz = R2.w;
    float acx = R3.x, acy = R3.y, acz = R3.z;
    float bcx = R3.w, bcy = R4.x, bcz = R4.y;

    float apx = px - ax, apy = py - ay, apz = pz - az;
    float d1 = (abx*apx + aby*apy) + abz*apz;
    float d2 = (acx*apx + acy*apy) + acz*apz;
    float bpx = px - bx, bpy = py - by, bpz = pz - bz;
    float d3 = (abx*bpx + aby*bpy) + abz*bpz;
    float d4 = (acx*bpx + acy*bpy) + acz*bpz;
    float cqx = px - cx, cqy = py - cy, cqz = pz - cz;
    float d5 = (abx*cqx + aby*cqy) + abz*cqz;
    float d6 = (acx*cqx + acy*cqy) + acz*cqz;

    float va = d3*d6 - d5*d4;
    float vb = d5*d2 - d1*d6;
    float vc = d1*d4 - d3*d2;
    float u43 = d4 - d3;
    float u56 = d5 - d6;

    bool c1 = (d1 <= 0.0f) && (d2 <= 0.0f);
    bool c2 = (d3 >= 0.0f) && (d4 <= d3);
    bool c3 = (d6 >= 0.0f) && (d5 <= d6);
    bool c4 = (vc <= 0.0f) && (d1 >= 0.0f) && (d3 <= 0.0f);
    bool c5 = (vb <= 0.0f) && (d2 >= 0.0f) && (d6 <= 0.0f);
    bool c6 = (va <= 0.0f) && (u43 >= 0.0f) && (u56 >= 0.0f);

    int reg = c1 ? 0 : (c2 ? 1 : (c3 ? 2 : (c4 ? 3 : (c5 ? 4 : (c6 ? 5 : 6)))));

    float denom = fmaxf((va + vb) + vc, EPSF);
    float den1 = (reg == 3) ? fmaxf(d1 - d3, EPSF)
               : (reg == 5) ? fmaxf(u43 + u56, EPSF)
               : (reg == 6) ? denom : 1.0f;
    float num1 = (reg == 3) ? d1
               : (reg == 5) ? u43
               : (reg == 6) ? vb : 0.0f;
    float den2 = (reg == 4) ? fmaxf(d2 - d6, EPSF)
               : (reg == 6) ? denom : 1.0f;
    float num2 = (reg == 4) ? d2
               : (reg == 6) ? vc : 0.0f;
    float s = num1 / den1;
    float t = num2 / den2;

    bool useB = (reg == 1) || (reg == 5);
    bool useC = (reg == 2);
    float basex = useB ? bx : (useC ? cx : ax);
    float basey = useB ? by : (useC ? cy : ay);
    float basez = useB ? bz : (useC ? cz : az);
    bool e1bc = (reg == 5);
    float e1x = e1bc ? bcx : abx;
    float e1y = e1bc ? bcy : aby;
    float e1z = e1bc ? bcz : abz;

    float cpx = (basex + e1x*s) + acx*t;
    float cpy = (basey + e1y*s) + acy*t;
    float cpz = (basez + e1z*s) + acz*t;
    float rx = px - cpx, ry = py - cpy, rz = pz - cpz;
    return (rx*rx + ry*ry) + rz*rz;
}

// ---------------------------------------------------------------------------
// Fast-path record + eval (trimmed formulation, validated absmax 0.0).
// ---------------------------------------------------------------------------
struct Rec { f2 v[NCONST]; };

__device__ __forceinline__ Rec loadRec(const f2* p) {
    Rec r;
#pragma unroll
    for (int i = 0; i < NCONST; ++i) r.v[i] = p[i];
    return r;
}

__device__ __forceinline__ void evalRec(
    const Rec& r, const f2* X, const f2* Y, const f2* Z, const f2* W, f2* m)
{
    f2 abx=r.v[0], aby=r.v[1], abz=r.v[2], ka1=r.v[3];
    f2 acx=r.v[4], acy=r.v[5], acz=r.v[6], ka2=r.v[7];
    f2 ax=r.v[8],  ay=r.v[9],  az=r.v[10], aa=r.v[11];
    f2 ab2=r.v[12], ac2=r.v[13], abac=r.v[14], bc2=r.v[15];
    f2 kbc=r.v[16], iab2=r.v[17], iac2=r.v[18], ibc2=r.v[19];
    f2 inn=r.v[20], nn=r.v[21];

#pragma unroll
    for (int k = 0; k < 8; ++k) {
        f2 sab = vfma(abx, X[k], vfma(aby, Y[k], abz * Z[k]));
        f2 sac = vfma(acx, X[k], vfma(acy, Y[k], acz * Z[k]));
        f2 adp = vfma(ax,  X[k], vfma(ay,  Y[k], az  * Z[k]));

        f2 d1 = sab - ka1, d2 = sac - ka2;
        f2 ap2 = vfma(bc(-2.0f), adp, W[k]) + aa;   // +inf if poisoned
        f2 bp2 = vfma(bc(-2.0f), d1, ap2) + ab2;

        f2 sA = clamp01(d1 * iab2);
        f2 dAB = vfma(-sA, vfma(-sA, ab2, d1 + d1), ap2);
        f2 sC = clamp01(d2 * iac2);
        f2 dAC = vfma(-sC, vfma(-sC, ac2, d2 + d2), ap2);
        f2 u43 = (d2 - d1) + kbc;
        f2 sB = clamp01(u43 * ibc2);
        f2 dBC = vfma(-sB, vfma(-sB, bc2, u43 + u43), bp2);

        f2 v = vfma(ac2, d1, -(abac * d2));      // == reference vb
        f2 w = vfma(ab2, d2, -(abac * d1));      // == reference vc
        f2 s = v + w;
        f2 dprod = vfma(w, d2, v * d1);
        f2 dIN = vfma(-dprod, inn, ap2);         // ap2 - |inplane|^2
        f2 g = vmin2(vmin2(v, w), nn - s);       // inside iff g >= 0
        f2 dI = vfma(vmin2(g, bc(0.0f)), bc(-1e30f), dIN);

        m[k] = vmin2(m[k], vmin2(vmin2(dAB, dAC), vmin2(dBC, dI)));
    }
}

// ---------------------------------------------------------------------------
// Kernel 2: 8 points/thread, two triangles per packed op, 64 tris/block,
// ping-pong SGPR prefetch of the wave-uniform constant record.
// ---------------------------------------------------------------------------
__global__ __launch_bounds__(256) void dist_kernel(
    const float* __restrict__ pts, const f2* __restrict__ pair,
    const float4* __restrict__ sa, const unsigned long long* __restrict__ mask,
    unsigned int* __restrict__ minD)
{
    const float INF = __uint_as_float(0x7F800000u);
    int tid   = threadIdx.x;
    int pg    = blockIdx.x;        // 0 .. 7
    int slice = blockIdx.y;        // 0 .. 127

    int b  = pg >> 2;              // 4 point-groups per batch
    int p0 = pg * PTS_PER_BLOCK + tid;

    f2 X[8], Y[8], Z[8], W[8], m[8];
#pragma unroll
    for (int k = 0; k < 8; ++k) {
        int p = p0 + k * 256;
        X[k] = bc(pts[p*3+0]); Y[k] = bc(pts[p*3+1]); Z[k] = bc(pts[p*3+2]);
        W[k] = vfma(X[k], X[k], vfma(Y[k], Y[k], Z[k] * Z[k]));
        m[k] = bc(INF);
    }

    int t0 = b * FF + slice * CHUNK_T;
    const f2* cb = pair + (size_t)(t0 >> 1) * NCONST;

    Rec A = loadRec(cb);
#pragma unroll 1
    for (int tp = 0; tp < CHUNK_T / 2; tp += 2) {
        Rec Bx = loadRec(cb + (tp + 1) * NCONST);   // prefetch next
        evalRec(A, X, Y, Z, W, m);
        A = loadRec(cb + (tp + 2) * NCONST);        // prefetch next-next (padded)
        evalRec(Bx, X, Y, Z, W, m);
    }

    // Phase B: bit-exact eval for flagged slivers (one mask word per block)
    unsigned long long bits = mask[t0 >> 6];
    while (bits) {
        int bit = __builtin_ctzll(bits);
        bits &= bits - 1;
        const float4* sb = sa + (size_t)(t0 + bit) * SLOW_F4;
        float4 S0 = sb[0], S1 = sb[1], S2 = sb[2], S3 = sb[3], S4 = sb[4];
#pragma unroll
        for (int k = 0; k < 8; ++k)
            m[k].x = fminf(m[k].x, tri_d2(X[k].x, Y[k].x, Z[k].x, S0, S1, S2, S3, S4));
    }

    // fold halves, clamp (monotone), float-as-uint atomicMin (values >= 0)
#pragma unroll
    for (int k = 0; k < 8; ++k) {
        float r = fminf(m[k].x, m[k].y);
        atomicMin(&minD[p0 + k*256], __float_as_uint(fmaxf(r, 0.0f)));
    }
}

// ---------------------------------------------------------------------------
// Kernel 3: one block per batch (1024 threads); sum + y-extent + atomicAdd
// of this batch's loss term into out (zeroed by precompute).
// ---------------------------------------------------------------------------
__global__ __launch_bounds__(1024) void reduce_kernel(
    const unsigned int* __restrict__ minD, const float* __restrict__ verts,
    float* __restrict__ out)
{
    int b = blockIdx.x;
    int tid = threadIdx.x;

    float s = 0.0f;
    for (int i = tid; i < PP; i += 1024)
        s += __uint_as_float(minD[b * PP + i]);

    float ymin = 3.4e38f, ymax = -3.4e38f;
    for (int i = tid; i < VV; i += 1024) {
        float y = verts[((size_t)b * VV + i) * 3 + 1];
        ymin = fminf(ymin, y); ymax = fmaxf(ymax, y);
    }

    for (int off = 32; off > 0; off >>= 1) {
        s += __shfl_down(s, off);
        ymin = fminf(ymin, __shfl_down(ymin, off));
        ymax = fmaxf(ymax, __shfl_down(ymax, off));
    }

    __shared__ float shs[16], shmn[16], shmx[16];
    if ((tid & 63) == 0) {
        int w = tid >> 6;
        shs[w] = s; shmn[w] = ymin; shmx[w] = ymax;
    }
    __syncthreads();
    if (tid == 0) {
        float tot = shs[0], mn = shmn[0], mx = shmx[0];
        for (int w = 1; w < 16; ++w) {
            tot += shs[w];
            mn = fminf(mn, shmn[w]);
            mx = fmaxf(mx, shmx[w]);
        }
        atomicAdd(out, 0.5f * sqrtf(tot) / (mx - mn));  // mean over B=2
    }
}

// ---------------------------------------------------------------------------
extern "C" void kernel_launch(void* const* d_in, const int* in_sizes, int n_in,
                              void* d_out, int out_size, void* d_ws, size_t ws_size,
                              hipStream_t stream) {
    const float* pts   = (const float*)d_in[0];   // [B,P,3]
    const float* verts = (const float*)d_in[1];   // [B,V,3]
    const int*   faces = (const int*)d_in[2];     // [B,F,3]
    float* out = (float*)d_out;

    char* w = (char*)d_ws;
    float* pairrec = (float*)w;                        // 2.75 MB (+pad)
    w += ((size_t)(BB * FF / 2) + 2) * (2 * NCONST) * sizeof(float);
    float4* slowrec = (float4*)w;                      // 1.25 MB (sparse use)
    w += (size_t)BB * FF * SLOW_F4 * sizeof(float4);
    unsigned long long* mask = (unsigned long long*)w; // 2 KB
    w += (size_t)(BB * FF / 64) * sizeof(unsigned long long);
    unsigned int* minD = (unsigned int*)w;             // 64 KB

    precompute_kernel<<<(BB * FF + 255) / 256, 256, 0, stream>>>(
        verts, faces, pairrec, slowrec, mask, minD, out);

    dim3 grid(BB * PP / PTS_PER_BLOCK, NSLICES);   // 8 x 128 = 1024 blocks
    dist_kernel<<<grid, 256, 0, stream>>>(
        pts, (const f2*)pairrec, slowrec, mask, minD);

    reduce_kernel<<<BB, 1024, 0, stream>>>(minD, verts, out);
}

// Round 14
// 195.466 us; speedup vs baseline: 1.0571x; 1.0571x over previous
//
#include <hip/hip_runtime.h>

#define EPSF 1e-12f
constexpr int BB = 2;
constexpr int PP = 8192;
constexpr int VV = 4098;
constexpr int FF = 8192;

constexpr int SLOW_F4 = 5;            // verbatim record: 5 x float4
constexpr int NCONST = 22;            // fast consts per triangle
constexpr int PTS_PER_BLOCK = 1024;   // 4 points/thread x 256 threads
constexpr int NSLICES = 128;
constexpr int CHUNK_T = FF / NSLICES; // 64 tris/block = 1 mask word

typedef float f2 __attribute__((ext_vector_type(2)));

__device__ __forceinline__ f2 vfma(f2 a, f2 b, f2 c) {
#if __has_builtin(__builtin_elementwise_fma)
    return __builtin_elementwise_fma(a, b, c);
#else
    return (f2){fmaf(a.x, b.x, c.x), fmaf(a.y, b.y, c.y)};
#endif
}
__device__ __forceinline__ f2 vmin2(f2 a, f2 b) { return __builtin_elementwise_min(a, b); }
__device__ __forceinline__ f2 vmax2(f2 a, f2 b) { return __builtin_elementwise_max(a, b); }
__device__ __forceinline__ f2 bc(float s) { return (f2){s, s}; }
__device__ __forceinline__ f2 clamp01(f2 x) { return vmin2(vmax2(x, bc(0.0f)), bc(1.0f)); }

// ---------------------------------------------------------------------------
// Kernel 1: pair-interleaved fast records + slow records + sliver mask + inits.
// Fast consts per tri (c): 0-2 ab, 3 ka1, 4-6 ac, 7 ka2, 8-10 a, 11 aa*,
// 12 ab2, 13 ac2, 14 abac, 15 bc2, 16 kbc=ab2-abac, 17 iab2, 18 iac2,
// 19 ibc2, 20 inn, 21 nn.  Interleaved per tri-PAIR (f2 = even,odd tri ->
// wave-uniform SGPR pair, direct v_pk operand).
// Sliver poisoning: aa*=+inf => ap2/bp2/dAB/dAC/dBC/dIN all +inf (no 0*inf).
// ---------------------------------------------------------------------------
__global__ __launch_bounds__(256) void precompute_kernel(
    const float* __restrict__ verts, const int* __restrict__ faces,
    float* __restrict__ pairrec, float4* __restrict__ slowrec,
    unsigned long long* __restrict__ mask, unsigned int* __restrict__ minD,
    float* __restrict__ out)
{
    int idx = blockIdx.x * 256 + threadIdx.x;   // grid exactly covers BB*FF
    if (idx == 0) out[0] = 0.0f;                // reduce atomicAdds into it
    if (idx < BB * PP) minD[idx] = 0x7F800000u; // +inf
    if (idx >= BB * FF) return;

    int b = idx / FF;
    const float* vb = verts + (size_t)b * VV * 3;
    int i0 = faces[idx * 3 + 0];
    int i1 = faces[idx * 3 + 1];
    int i2 = faces[idx * 3 + 2];

    float ax = vb[i0*3+0], ay = vb[i0*3+1], az = vb[i0*3+2];
    float bx = vb[i1*3+0], by = vb[i1*3+1], bz = vb[i1*3+2];
    float cx = vb[i2*3+0], cy = vb[i2*3+1], cz = vb[i2*3+2];

    // plain fp32 subs: bit-match numpy (shared by both records)
    float abx = bx-ax, aby = by-ay, abz = bz-az;
    float acx = cx-ax, acy = cy-ay, acz = cz-az;
    float bcx = cx-bx, bcy = cy-by, bcz = cz-bz;

    {   // slow record (read only for flagged tris)
        float4* t = slowrec + (size_t)idx * SLOW_F4;
        t[0] = make_float4(ax, ay, az, abx);
        t[1] = make_float4(bx, by, bz, aby);
        t[2] = make_float4(cx, cy, cz, abz);
        t[3] = make_float4(acx, acy, acz, bcx);
        t[4] = make_float4(bcy, bcz, 0.0f, 0.0f);
    }

    float nx = aby*acz - abz*acy;
    float ny = abz*acx - abx*acz;
    float nz = abx*acy - aby*acx;

    float ka1  = abx*ax + aby*ay + abz*az;
    float ka2  = acx*ax + acy*ay + acz*az;
    float aa   = ax*ax + ay*ay + az*az;
    float abac = abx*acx + aby*acy + abz*acz;

    float ab2 = abx*abx + aby*aby + abz*abz;
    float ac2 = acx*acx + acy*acy + acz*acz;
    float bc2 = bcx*bcx + bcy*bcy + bcz*bcz;
    float nn  = nx*nx + ny*ny + nz*nz;

    float inv_ab2 = 1.0f / fmaxf(ab2, EPSF);
    float inv_ac2 = 1.0f / fmaxf(ac2, EPSF);
    float inv_bc2 = 1.0f / fmaxf(bc2, EPSF);
    float inv_nn  = 1.0f / fmaxf(nn,  EPSF);

    // sliver/degenerate classifier: sin^2(angle at a) <= 3e-2 or tiny edges
    bool slowtri = !((nn > 0.03f * (ab2 * ac2)) &&
                     (ab2 > 1e-4f) && (ac2 > 1e-4f) && (bc2 > 1e-4f));

    unsigned long long mb = __ballot(slowtri);
    if ((threadIdx.x & 63) == 0) mask[idx >> 6] = mb;

    float INF = __uint_as_float(0x7F800000u);
    float cvals[NCONST] = {
        abx, aby, abz, ka1,
        acx, acy, acz, ka2,
        ax,  ay,  az,  slowtri ? INF : aa,
        ab2, ac2, abac, bc2,
        ab2 - abac, inv_ab2, inv_ac2, inv_bc2,
        inv_nn, nn
    };
    float* pr = pairrec + (size_t)(idx >> 1) * (2 * NCONST) + (idx & 1);
#pragma unroll
    for (int c = 0; c < NCONST; ++c) pr[2*c] = cvals[c];
}

// ---------------------------------------------------------------------------
// Verbatim fp32 port (bit-exact vs numpy) — slivers only. Proven in R3.
// ---------------------------------------------------------------------------
__device__ __forceinline__ float tri_d2(
    float px, float py, float pz,
    float4 R0, float4 R1, float4 R2, float4 R3, float4 R4)
{
#pragma clang fp contract(off)
    float ax = R0.x, ay = R0.y, az = R0.z;
    float bx = R1.x, by = R1.y, bz = R1.z;
    float cx = R2.x, cy = R2.y, cz = R2.z;
    float abx = R0.w, aby = R1.w, abz = R2.w;
    float acx = R3.x, acy = R3.y, acz = R3.z;
    float bcx = R3.w, bcy = R4.x, bcz = R4.y;

    float apx = px - ax, apy = py - ay, apz = pz - az;
    float d1 = (abx*apx + aby*apy) + abz*apz;
    float d2 = (acx*apx + acy*apy) + acz*apz;
    float bpx = px - bx, bpy = py - by, bpz = pz - bz;
    float d3 = (abx*bpx + aby*bpy) + abz*bpz;
    float d4 = (acx*bpx + acy*bpy) + acz*bpz;
    float cqx = px - cx, cqy = py - cy, cqz = pz - cz;
    float d5 = (abx*cqx + aby*cqy) + abz*cqz;
    float d6 = (acx*cqx + acy*cqy) + acz*cqz;

    float va = d3*d6 - d5*d4;
    float vb = d5*d2 - d1*d6;
    float vc = d1*d4 - d3*d2;
    float u43 = d4 - d3;
    float u56 = d5 - d6;

    bool c1 = (d1 <= 0.0f) && (d2 <= 0.0f);
    bool c2 = (d3 >= 0.0f) && (d4 <= d3);
    bool c3 = (d6 >= 0.0f) && (d5 <= d6);
    bool c4 = (vc <= 0.0f) && (d1 >= 0.0f) && (d3 <= 0.0f);
    bool c5 = (vb <= 0.0f) && (d2 >= 0.0f) && (d6 <= 0.0f);
    bool c6 = (va <= 0.0f) && (u43 >= 0.0f) && (u56 >= 0.0f);

    int reg = c1 ? 0 : (c2 ? 1 : (c3 ? 2 : (c4 ? 3 : (c5 ? 4 : (c6 ? 5 : 6)))));

    float denom = fmaxf((va + vb) + vc, EPSF);
    float den1 = (reg == 3) ? fmaxf(d1 - d3, EPSF)
               : (reg == 5) ? fmaxf(u43 + u56, EPSF)
               : (reg == 6) ? denom : 1.0f;
    float num1 = (reg == 3) ? d1
               : (reg == 5) ? u43
               : (reg == 6) ? vb : 0.0f;
    float den2 = (reg == 4) ? fmaxf(d2 - d6, EPSF)
               : (reg == 6) ? denom : 1.0f;
    float num2 = (reg == 4) ? d2
               : (reg == 6) ? vc : 0.0f;
    float s = num1 / den1;
    float t = num2 / den2;

    bool useB = (reg == 1) || (reg == 5);
    bool useC = (reg == 2);
    float basex = useB ? bx : (useC ? cx : ax);
    float basey = useB ? by : (useC ? cy : ay);
    float basez = useB ? bz : (useC ? cz : az);
    bool e1bc = (reg == 5);
    float e1x = e1bc ? bcx : abx;
    float e1y = e1bc ? bcy : aby;
    float e1z = e1bc ? bcz : abz;

    float cpx = (basex + e1x*s) + acx*t;
    float cpy = (basey + e1y*s) + acy*t;
    float cpz = (basez + e1z*s) + acz*t;
    float rx = px - cpx, ry = py - cpy, rz = pz - cpz;
    return (rx*rx + ry*ry) + rz*rz;
}

// ---------------------------------------------------------------------------
// Fast-path record + eval (trimmed formulation, validated absmax 0.0 in R10).
// ---------------------------------------------------------------------------
struct Rec { f2 v[NCONST]; };

__device__ __forceinline__ Rec loadRec(const f2* p) {
    Rec r;
#pragma unroll
    for (int i = 0; i < NCONST; ++i) r.v[i] = p[i];
    return r;
}

__device__ __forceinline__ void evalRec(
    const Rec& r, const f2* X, const f2* Y, const f2* Z, const f2* W, f2* m)
{
    f2 abx=r.v[0], aby=r.v[1], abz=r.v[2], ka1=r.v[3];
    f2 acx=r.v[4], acy=r.v[5], acz=r.v[6], ka2=r.v[7];
    f2 ax=r.v[8],  ay=r.v[9],  az=r.v[10], aa=r.v[11];
    f2 ab2=r.v[12], ac2=r.v[13], abac=r.v[14], bc2=r.v[15];
    f2 kbc=r.v[16], iab2=r.v[17], iac2=r.v[18], ibc2=r.v[19];
    f2 inn=r.v[20], nn=r.v[21];

#pragma unroll
    for (int k = 0; k < 4; ++k) {
        f2 sab = vfma(abx, X[k], vfma(aby, Y[k], abz * Z[k]));
        f2 sac = vfma(acx, X[k], vfma(acy, Y[k], acz * Z[k]));
        f2 adp = vfma(ax,  X[k], vfma(ay,  Y[k], az  * Z[k]));

        f2 d1 = sab - ka1, d2 = sac - ka2;
        f2 ap2 = vfma(bc(-2.0f), adp, W[k]) + aa;   // +inf if poisoned
        f2 bp2 = vfma(bc(-2.0f), d1, ap2) + ab2;

        f2 sA = clamp01(d1 * iab2);
        f2 dAB = vfma(-sA, vfma(-sA, ab2, d1 + d1), ap2);
        f2 sC = clamp01(d2 * iac2);
        f2 dAC = vfma(-sC, vfma(-sC, ac2, d2 + d2), ap2);
        f2 u43 = (d2 - d1) + kbc;
        f2 sB = clamp01(u43 * ibc2);
        f2 dBC = vfma(-sB, vfma(-sB, bc2, u43 + u43), bp2);

        f2 v = vfma(ac2, d1, -(abac * d2));      // == reference vb
        f2 w = vfma(ab2, d2, -(abac * d1));      // == reference vc
        f2 s = v + w;
        f2 dprod = vfma(w, d2, v * d1);
        f2 dIN = vfma(-dprod, inn, ap2);         // ap2 - |inplane|^2
        f2 g = vmin2(vmin2(v, w), nn - s);       // inside iff g >= 0
        f2 dI = vfma(vmin2(g, bc(0.0f)), bc(-1e30f), dIN);

        m[k] = vmin2(m[k], vmin2(vmin2(dAB, dAC), vmin2(dBC, dI)));
    }
}

// ---------------------------------------------------------------------------
// Kernel 2: 4 points/thread, two triangles per packed op, 64 tris/block,
// ping-pong prefetch of the wave-uniform constant record (SMEM latency
// overlapped with packed compute; pairrec padded by 2 records).
// ---------------------------------------------------------------------------
__global__ __launch_bounds__(256) void dist_kernel(
    const float* __restrict__ pts, const f2* __restrict__ pair,
    const float4* __restrict__ sa, const unsigned long long* __restrict__ mask,
    unsigned int* __restrict__ minD)
{
    const float INF = __uint_as_float(0x7F800000u);
    int tid   = threadIdx.x;
    int pg    = blockIdx.x;        // 0 .. 15
    int slice = blockIdx.y;        // 0 .. 127

    int b  = pg >> 3;              // 8 point-groups per batch
    int p0 = pg * PTS_PER_BLOCK + tid;

    f2 X[4], Y[4], Z[4], W[4], m[4];
#pragma unroll
    for (int k = 0; k < 4; ++k) {
        int p = p0 + k * 256;
        X[k] = bc(pts[p*3+0]); Y[k] = bc(pts[p*3+1]); Z[k] = bc(pts[p*3+2]);
        W[k] = vfma(X[k], X[k], vfma(Y[k], Y[k], Z[k] * Z[k]));
        m[k] = bc(INF);
    }

    int t0 = b * FF + slice * CHUNK_T;
    const f2* cb = pair + (size_t)(t0 >> 1) * NCONST;

    Rec A = loadRec(cb);
#pragma unroll 1
    for (int tp = 0; tp < CHUNK_T / 2; tp += 2) {
        Rec Bx = loadRec(cb + (tp + 1) * NCONST);   // prefetch next
        evalRec(A, X, Y, Z, W, m);
        A = loadRec(cb + (tp + 2) * NCONST);        // prefetch next-next (padded)
        evalRec(Bx, X, Y, Z, W, m);
    }

    // Phase B: bit-exact eval for flagged slivers (one mask word per block)
    unsigned long long bits = mask[t0 >> 6];
    while (bits) {
        int bit = __builtin_ctzll(bits);
        bits &= bits - 1;
        const float4* sb = sa + (size_t)(t0 + bit) * SLOW_F4;
        float4 S0 = sb[0], S1 = sb[1], S2 = sb[2], S3 = sb[3], S4 = sb[4];
#pragma unroll
        for (int k = 0; k < 4; ++k)
            m[k].x = fminf(m[k].x, tri_d2(X[k].x, Y[k].x, Z[k].x, S0, S1, S2, S3, S4));
    }

    // fold halves, clamp (monotone), float-as-uint atomicMin (values >= 0)
#pragma unroll
    for (int k = 0; k < 4; ++k) {
        float r = fminf(m[k].x, m[k].y);
        atomicMin(&minD[p0 + k*256], __float_as_uint(fmaxf(r, 0.0f)));
    }
}

// ---------------------------------------------------------------------------
// Kernel 3: one block per batch (1024 threads); sum + y-extent + atomicAdd
// of this batch's loss term into out (zeroed by precompute).
// ---------------------------------------------------------------------------
__global__ __launch_bounds__(1024) void reduce_kernel(
    const unsigned int* __restrict__ minD, const float* __restrict__ verts,
    float* __restrict__ out)
{
    int b = blockIdx.x;
    int tid = threadIdx.x;

    float s = 0.0f;
    for (int i = tid; i < PP; i += 1024)
        s += __uint_as_float(minD[b * PP + i]);

    float ymin = 3.4e38f, ymax = -3.4e38f;
    for (int i = tid; i < VV; i += 1024) {
        float y = verts[((size_t)b * VV + i) * 3 + 1];
        ymin = fminf(ymin, y); ymax = fmaxf(ymax, y);
    }

    for (int off = 32; off > 0; off >>= 1) {
        s += __shfl_down(s, off);
        ymin = fminf(ymin, __shfl_down(ymin, off));
        ymax = fmaxf(ymax, __shfl_down(ymax, off));
    }

    __shared__ float shs[16], shmn[16], shmx[16];
    if ((tid & 63) == 0) {
        int w = tid >> 6;
        shs[w] = s; shmn[w] = ymin; shmx[w] = ymax;
    }
    __syncthreads();
    if (tid == 0) {
        float tot = shs[0], mn = shmn[0], mx = shmx[0];
        for (int w = 1; w < 16; ++w) {
            tot += shs[w];
            mn = fminf(mn, shmn[w]);
            mx = fmaxf(mx, shmx[w]);
        }
        atomicAdd(out, 0.5f * sqrtf(tot) / (mx - mn));  // mean over B=2
    }
}

// ---------------------------------------------------------------------------
extern "C" void kernel_launch(void* const* d_in, const int* in_sizes, int n_in,
                              void* d_out, int out_size, void* d_ws, size_t ws_size,
                              hipStream_t stream) {
    const float* pts   = (const float*)d_in[0];   // [B,P,3]
    const float* verts = (const float*)d_in[1];   // [B,V,3]
    const int*   faces = (const int*)d_in[2];     // [B,F,3]
    float* out = (float*)d_out;

    char* w = (char*)d_ws;
    float* pairrec = (float*)w;                        // 2.75 MB (+pad)
    w += ((size_t)(BB * FF / 2) + 2) * (2 * NCONST) * sizeof(float);
    float4* slowrec = (float4*)w;                      // 1.25 MB
    w += (size_t)BB * FF * SLOW_F4 * sizeof(float4);
    unsigned long long* mask = (unsigned long long*)w; // 2 KB
    w += (size_t)(BB * FF / 64) * sizeof(unsigned long long);
    unsigned int* minD = (unsigned int*)w;             // 64 KB

    precompute_kernel<<<(BB * FF + 255) / 256, 256, 0, stream>>>(
        verts, faces, pairrec, slowrec, mask, minD, out);

    dim3 grid(BB * PP / PTS_PER_BLOCK, NSLICES);   // 16 x 128 = 2048 blocks
    dist_kernel<<<grid, 256, 0, stream>>>(
        pts, (const f2*)pairrec, slowrec, mask, minD);

    reduce_kernel<<<BB, 1024, 0, stream>>>(minD, verts, out);
}